// Round 6
// baseline (248.332 us; speedup 1.0000x reference)
//
#include <hip/hip_runtime.h>
#include <hip/hip_bf16.h>

#define D 128
#define SCAN_BLK 256
#define SCAN_VPT 4
#define SCAN_TILE (SCAN_BLK * SCAN_VPT)   // 1024

typedef __attribute__((ext_vector_type(8))) short short8;   // 8 bf16
typedef __attribute__((ext_vector_type(4))) float f32x4;    // MFMA C/D frag

// ---------------------------------------------------------------------------
// prep_zero: WT transpose->bf16, bsum = bl+br, zero deg cursors + scan state.
// (replaces memset + prep_w: one dispatch instead of two)
// ---------------------------------------------------------------------------
__global__ __launch_bounds__(256) void prep_zero(
    const float* __restrict__ Wl, const float* __restrict__ Wr,
    const float* __restrict__ bl, const float* __restrict__ br,
    __hip_bfloat16* __restrict__ WTl, __hip_bfloat16* __restrict__ WTr,
    float* __restrict__ bsum, int* __restrict__ pos,
    unsigned long long* __restrict__ scan_state, int n_nodes) {
  const int gtid = blockIdx.x * 256 + threadIdx.x;
  const int gsz = gridDim.x * 256;
  for (int i = gtid; i < D * D; i += gsz) {
    const int n = i >> 7, k = i & 127;
    WTl[n * D + k] = __float2bfloat16(Wl[k * D + n]);
    WTr[n * D + k] = __float2bfloat16(Wr[k * D + n]);
  }
  if (gtid < D) bsum[gtid] = bl[gtid] + br[gtid];
  for (int i = gtid; i < n_nodes; i += gsz) pos[i] = 0;
  if (gtid < 128) scan_state[gtid] = 0ull;
}

// ---------------------------------------------------------------------------
// gemm_h: h = bf16(x @ Wl), with degree histogram as grid-stride prologue.
// ---------------------------------------------------------------------------
__global__ __launch_bounds__(256) void gemm_h(
    const float* __restrict__ x, const __hip_bfloat16* __restrict__ WTl,
    __hip_bfloat16* __restrict__ h,
    const int* __restrict__ edst, int* __restrict__ deg, int n_edges,
    int n_rowtiles) {
  const int gsz = gridDim.x * 256;
  for (int e = blockIdx.x * 256 + threadIdx.x; e < n_edges; e += gsz)
    atomicAdd(&deg[edst[e]], 1);

  __shared__ __hip_bfloat16 xs[16][136];   // +8 pad
  const int t = threadIdx.x;
  const int wave = t >> 6;
  const int lane = t & 63;
  const int m = lane & 15;
  const int q = lane >> 4;

  short8 bfrag[2][4];
#pragma unroll
  for (int c = 0; c < 2; ++c) {
    const int n0 = wave * 32 + c * 16;
#pragma unroll
    for (int ks = 0; ks < 4; ++ks)
      bfrag[c][ks] = *(const short8*)&WTl[(n0 + m) * D + ks * 32 + q * 8];
  }

  const int srow = t >> 4;
  const int scol = (t & 15) * 8;

  for (int rt = blockIdx.x; rt < n_rowtiles; rt += gridDim.x) {
    const int rowbase = rt * 16;
    {
      const float4* src = (const float4*)&x[(size_t)(rowbase + srow) * D + scol];
      const float4 v0 = src[0], v1 = src[1];
      __hip_bfloat16* dst = &xs[srow][scol];
      dst[0] = __float2bfloat16(v0.x); dst[1] = __float2bfloat16(v0.y);
      dst[2] = __float2bfloat16(v0.z); dst[3] = __float2bfloat16(v0.w);
      dst[4] = __float2bfloat16(v1.x); dst[5] = __float2bfloat16(v1.y);
      dst[6] = __float2bfloat16(v1.z); dst[7] = __float2bfloat16(v1.w);
    }
    __syncthreads();
    f32x4 acc[2];
#pragma unroll
    for (int c = 0; c < 2; ++c)
#pragma unroll
      for (int r = 0; r < 4; ++r) acc[c][r] = 0.f;
#pragma unroll
    for (int ks = 0; ks < 4; ++ks) {
      const short8 afrag = *(const short8*)&xs[m][ks * 32 + q * 8];
#pragma unroll
      for (int c = 0; c < 2; ++c)
        acc[c] = __builtin_amdgcn_mfma_f32_16x16x32_bf16(afrag, bfrag[c][ks], acc[c], 0, 0, 0);
    }
#pragma unroll
    for (int c = 0; c < 2; ++c) {
      const int n = wave * 32 + c * 16 + m;
#pragma unroll
      for (int r = 0; r < 4; ++r)
        h[(size_t)(rowbase + q * 4 + r) * D + n] = __float2bfloat16(acc[c][r]);
    }
    __syncthreads();
  }
}

// ---------------------------------------------------------------------------
// scan_lb: single-pass exclusive scan of deg -> offsets + pos cursors, using
// decoupled lookback (state zeroed by prep_zero; 98 blocks all co-resident on
// 256 CUs so the spin cannot deadlock). Replaces scan1+scan3.
// state[b] = flag(hi32) | value(lo32); flag 1 = block sum, 2 = incl. prefix.
// ---------------------------------------------------------------------------
__global__ __launch_bounds__(SCAN_BLK) void scan_lb(
    const int* __restrict__ deg, int* __restrict__ offsets,
    int* __restrict__ pos, unsigned long long* __restrict__ state,
    int n, int n_edges) {
  __shared__ int sdata[SCAN_BLK];
  __shared__ int s_base;
  const int t = threadIdx.x;
  const int b = blockIdx.x;
  const int base = b * SCAN_TILE + t * SCAN_VPT;

  int v[SCAN_VPT];
  int s = 0;
#pragma unroll
  for (int j = 0; j < SCAN_VPT; ++j) {
    v[j] = (base + j < n) ? deg[base + j] : 0;
    s += v[j];
  }
  sdata[t] = s;
  __syncthreads();
  for (int off = 1; off < SCAN_BLK; off <<= 1) {
    int xv = (t >= off) ? sdata[t - off] : 0;
    __syncthreads();
    sdata[t] += xv;
    __syncthreads();
  }
  const int excl = sdata[t] - s;
  const int total = sdata[SCAN_BLK - 1];

  if (t == 0) {
    if (b == 0) {
      __hip_atomic_store(&state[0], (2ull << 32) | (unsigned)total,
                         __ATOMIC_RELEASE, __HIP_MEMORY_SCOPE_AGENT);
      s_base = 0;
    } else {
      __hip_atomic_store(&state[b], (1ull << 32) | (unsigned)total,
                         __ATOMIC_RELEASE, __HIP_MEMORY_SCOPE_AGENT);
      int run = 0;
      int j = b - 1;
      while (true) {
        const unsigned long long st = __hip_atomic_load(
            &state[j], __ATOMIC_ACQUIRE, __HIP_MEMORY_SCOPE_AGENT);
        const unsigned flag = (unsigned)(st >> 32);
        if (flag == 0) { __builtin_amdgcn_s_sleep(1); continue; }
        run += (int)(unsigned)st;
        if (flag == 2) break;
        --j;
      }
      __hip_atomic_store(&state[b], (2ull << 32) | (unsigned)(run + total),
                         __ATOMIC_RELEASE, __HIP_MEMORY_SCOPE_AGENT);
      s_base = run;
    }
  }
  __syncthreads();

  int run2 = s_base + excl;
#pragma unroll
  for (int j = 0; j < SCAN_VPT; ++j) {
    const int i = base + j;
    if (i < n) {
      offsets[i] = run2;
      pos[i] = run2;
      run2 += v[j];
    }
  }
  if (b == 0 && t == 0) offsets[n] = n_edges;
}

// ---------------------------------------------------------------------------
// scatter: pairs[slot] = {src, bits(weight)} in dst-sorted order.
// ---------------------------------------------------------------------------
__global__ __launch_bounds__(256) void scatter_kernel(
    const int* __restrict__ esrc, const int* __restrict__ edst,
    const float* __restrict__ ew, int* __restrict__ pos,
    int2* __restrict__ pairs, int n_edges) {
  const int e = blockIdx.x * 256 + threadIdx.x;
  if (e >= n_edges) return;
  const int d = edst[e];
  const int slot = atomicAdd(&pos[d], 1);
  pairs[slot] = make_int2(esrc[e], __float_as_int(ew[e]));
}

// ---------------------------------------------------------------------------
// sage_out: fused root-GEMM + aggregation per 16-node tile.
//   phase 1: MFMA x @ Wr + bsum -> LDS tile ot[16][130]  (stride 130: bank =
//            (2*row+n)%32, distinct across the 4 q-rows -> conflict-free
//            stores; R4 showed 800k SQ_LDS_BANK_CONFLICT at stride 128)
//   phase 2: each wave aggregates 4 nodes' edges on top, writes out once.
// xs/ot share one LDS buffer (disjoint lifetimes, extra sync between).
// ---------------------------------------------------------------------------
__global__ __launch_bounds__(256) void sage_out(
    const float* __restrict__ x, const __hip_bfloat16* __restrict__ WTr,
    const float* __restrict__ bsum, const __hip_bfloat16* __restrict__ h,
    const int* __restrict__ offsets, const int2* __restrict__ pairs,
    float* __restrict__ out) {
  __shared__ __align__(16) char smraw[16 * 130 * 4];   // 8320 B
  __hip_bfloat16 (*xs)[136] = (__hip_bfloat16(*)[136])smraw;  // 4352 B used
  float (*ot)[130] = (float(*)[130])smraw;

  const int t = threadIdx.x;
  const int wave = t >> 6;
  const int lane = t & 63;
  const int m = lane & 15;
  const int q = lane >> 4;
  const int rowbase = blockIdx.x * 16;

  short8 bfrag[2][4];
#pragma unroll
  for (int c = 0; c < 2; ++c) {
    const int n0 = wave * 32 + c * 16;
#pragma unroll
    for (int ks = 0; ks < 4; ++ks)
      bfrag[c][ks] = *(const short8*)&WTr[(n0 + m) * D + ks * 32 + q * 8];
  }

  {
    const int srow = t >> 4;
    const int scol = (t & 15) * 8;
    const float4* src = (const float4*)&x[(size_t)(rowbase + srow) * D + scol];
    const float4 v0 = src[0], v1 = src[1];
    __hip_bfloat16* dst = &xs[srow][scol];
    dst[0] = __float2bfloat16(v0.x); dst[1] = __float2bfloat16(v0.y);
    dst[2] = __float2bfloat16(v0.z); dst[3] = __float2bfloat16(v0.w);
    dst[4] = __float2bfloat16(v1.x); dst[5] = __float2bfloat16(v1.y);
    dst[6] = __float2bfloat16(v1.z); dst[7] = __float2bfloat16(v1.w);
  }
  __syncthreads();

  f32x4 acc[2];
#pragma unroll
  for (int c = 0; c < 2; ++c)
#pragma unroll
    for (int r = 0; r < 4; ++r) acc[c][r] = 0.f;
#pragma unroll
  for (int ks = 0; ks < 4; ++ks) {
    const short8 afrag = *(const short8*)&xs[m][ks * 32 + q * 8];
#pragma unroll
    for (int c = 0; c < 2; ++c)
      acc[c] = __builtin_amdgcn_mfma_f32_16x16x32_bf16(afrag, bfrag[c][ks], acc[c], 0, 0, 0);
  }
  __syncthreads();   // xs dead; ot aliases the same LDS

#pragma unroll
  for (int c = 0; c < 2; ++c) {
    const int n = wave * 32 + c * 16 + m;
    const float b = bsum[n];
#pragma unroll
    for (int r = 0; r < 4; ++r)
      ot[q * 4 + r][n] = acc[c][r] + b;
  }
  __syncthreads();

  const __hip_bfloat162* __restrict__ h2 = (const __hip_bfloat162*)h;
#pragma unroll
  for (int j = 0; j < 4; ++j) {
    const int ln = wave * 4 + j;
    const int node = rowbase + ln;
    const int begin = offsets[node];
    const int end = offsets[node + 1];
    float2 a = *(const float2*)&ot[ln][2 * lane];
    int i = begin;
    for (; i + 4 <= end; i += 4) {
      const int2 p0 = pairs[i + 0];
      const int2 p1 = pairs[i + 1];
      const int2 p2 = pairs[i + 2];
      const int2 p3 = pairs[i + 3];
      const __hip_bfloat162 a0 = h2[(size_t)p0.x * (D / 2) + lane];
      const __hip_bfloat162 a1 = h2[(size_t)p1.x * (D / 2) + lane];
      const __hip_bfloat162 a2 = h2[(size_t)p2.x * (D / 2) + lane];
      const __hip_bfloat162 a3 = h2[(size_t)p3.x * (D / 2) + lane];
      const float w0 = __int_as_float(p0.y), w1 = __int_as_float(p1.y);
      const float w2 = __int_as_float(p2.y), w3 = __int_as_float(p3.y);
      a.x = fmaf(w0, __bfloat162float(a0.x), a.x);
      a.y = fmaf(w0, __bfloat162float(a0.y), a.y);
      a.x = fmaf(w1, __bfloat162float(a1.x), a.x);
      a.y = fmaf(w1, __bfloat162float(a1.y), a.y);
      a.x = fmaf(w2, __bfloat162float(a2.x), a.x);
      a.y = fmaf(w2, __bfloat162float(a2.y), a.y);
      a.x = fmaf(w3, __bfloat162float(a3.x), a.x);
      a.y = fmaf(w3, __bfloat162float(a3.y), a.y);
    }
    for (; i < end; ++i) {
      const int2 p = pairs[i];
      const __hip_bfloat162 av = h2[(size_t)p.x * (D / 2) + lane];
      const float w = __int_as_float(p.y);
      a.x = fmaf(w, __bfloat162float(av.x), a.x);
      a.y = fmaf(w, __bfloat162float(av.y), a.y);
    }
    *(float2*)&out[(size_t)node * D + 2 * lane] = a;
  }
}

// ---------------------------------------------------------------------------
extern "C" void kernel_launch(void* const* d_in, const int* in_sizes, int n_in,
                              void* d_out, int out_size, void* d_ws, size_t ws_size,
                              hipStream_t stream) {
  const float* x   = (const float*)d_in[0];
  const int* esrc  = (const int*)d_in[1];
  const int* edst  = (const int*)d_in[2];
  const float* ew  = (const float*)d_in[3];
  const float* Wl  = (const float*)d_in[4];
  const float* bl  = (const float*)d_in[5];
  const float* Wr  = (const float*)d_in[6];
  const float* br  = (const float*)d_in[7];
  float* out = (float*)d_out;

  const int n_nodes = in_sizes[0] / D;   // 100000
  const int n_edges = in_sizes[1];       // 600000

  // Workspace layout (16B aligned sections)
  char* ws = (char*)d_ws;
  size_t off = 0;
  __hip_bfloat16* h = (__hip_bfloat16*)(ws + off);      // 25.6 MB
  off += (size_t)n_nodes * D * sizeof(__hip_bfloat16);
  off = (off + 15) & ~15ull;
  int* offsets = (int*)(ws + off);
  off += (size_t)(n_nodes + 1) * sizeof(int);
  off = (off + 15) & ~15ull;
  int* pos = (int*)(ws + off);                          // degree, then cursors
  off += (size_t)n_nodes * sizeof(int);
  off = (off + 15) & ~15ull;
  unsigned long long* scan_state = (unsigned long long*)(ws + off);
  off += 128 * sizeof(unsigned long long);
  int2* pairs = (int2*)(ws + off);                      // 4.8 MB
  off += (size_t)n_edges * sizeof(int2);
  off = (off + 15) & ~15ull;
  __hip_bfloat16* WTl = (__hip_bfloat16*)(ws + off);
  off += (size_t)D * D * sizeof(__hip_bfloat16);
  __hip_bfloat16* WTr = (__hip_bfloat16*)(ws + off);
  off += (size_t)D * D * sizeof(__hip_bfloat16);
  float* bsum = (float*)(ws + off);
  off += D * sizeof(float);

  const int n_rowtiles = (n_nodes + 15) / 16;           // 6250

  prep_zero<<<256, 256, 0, stream>>>(Wl, Wr, bl, br, WTl, WTr, bsum, pos,
                                     scan_state, n_nodes);

  const int gemm_grid = n_rowtiles < 2048 ? n_rowtiles : 2048;
  gemm_h<<<gemm_grid, 256, 0, stream>>>(x, WTl, h, edst, pos, n_edges, n_rowtiles);

  const int nparts = (n_nodes + SCAN_TILE - 1) / SCAN_TILE;   // 98
  scan_lb<<<nparts, SCAN_BLK, 0, stream>>>(pos, offsets, pos, scan_state,
                                           n_nodes, n_edges);

  scatter_kernel<<<(n_edges + 255) / 256, 256, 0, stream>>>(esrc, edst, ew, pos, pairs, n_edges);

  sage_out<<<n_rowtiles, 256, 0, stream>>>(x, WTr, bsum, h, offsets, pairs, out);
}